// Round 3
// baseline (149.663 us; speedup 1.0000x reference)
//
#include <hip/hip_runtime.h>

// BatchIndependentLoss: SupCon-style loss, B=2048, V=2, D=256, N=4096.
// loss = -mean_i( lp_i - (W_i - e^{lp}*lp) / u_new[i%B] )
//   l_ij = (dot_ij - dot_ii)/T ; dot matrix is SYMMETRIC -> compute upper
//   triangle of 128x128 tiles only (528 of 1024); off-diag tiles feed both
//   row-band stats (direct) and col-band stats (transposed w/ col self-dot).
//   E_i  = sum_j exp(l_ij) (all j incl diag), W_i = sum_j exp(l_ij)*l_ij
//   pos col j = i^2048 subtracted analytically in finalize.
//   u_new[b] = 0.1*u[idx[b]] + 0.9*(E_b - exp(lp_b))
// 2 dispatches: prep (bf16 convert + self-dots + zero E/W/cnt), gemm_sym
// (MFMA + fused stats + last-block ticket finalize).
// R2 bug fixed: cnt sat at byte 65536 == Cm[0] -> clobbered by prep's bf16
// writes -> ticket never fired -> out stayed 0. Cm moved to byte 131072.

#define BSZ   2048
#define NROW  4096
#define DDIM  256
#define INVT  (1.0f / 0.07f)
#define NB    32                    // 4096 / 128 bands
#define NTILES (NB * (NB + 1) / 2)  // 528 upper-triangle tiles

typedef __attribute__((ext_vector_type(8))) __bf16 bf16x8;
typedef __attribute__((ext_vector_type(4))) float f32x4;

__device__ __forceinline__ short f2bs(float x) {
    __bf16 b = (__bf16)x;
    return __builtin_bit_cast(short, b);
}

__device__ __forceinline__ void ag_store(float* p, float v) {
    __hip_atomic_store(p, v, __ATOMIC_RELAXED, __HIP_MEMORY_SCOPE_AGENT);
}
__device__ __forceinline__ float ag_load(const float* p) {
    return __hip_atomic_load(p, __ATOMIC_RELAXED, __HIP_MEMORY_SCOPE_AGENT);
}

// contrast row i = v*B + b  ->  features row b*V + v  (fp32, 256 elems)
__device__ __forceinline__ const float* crow_ptr(const float* feats, int i) {
    return feats + (((i & (BSZ - 1)) * 2 + (i >> 11)) << 8);
}

// ---------------- prep: bf16 convert, self-dots, zero E/W/cnt --------------
__global__ __launch_bounds__(256) void prep_kernel(const float* __restrict__ feats,
        float* __restrict__ selfdot, float* __restrict__ EWzero,
        int* __restrict__ cnt, short* __restrict__ Cm) {
    int z = blockIdx.x * 256 + threadIdx.x;
    if (z < 2 * NROW) EWzero[z] = 0.0f;                  // zero E and W
    if (z == 0) __hip_atomic_store(cnt, 0, __ATOMIC_RELAXED, __HIP_MEMORY_SCOPE_AGENT);

    int lane = threadIdx.x & 63;
    int row  = (blockIdx.x << 2) + (threadIdx.x >> 6);   // 1024 blocks * 4 waves
    const float4* src = (const float4*)crow_ptr(feats, row);
    float4 v = src[lane];
    float a0 = (float)(__bf16)v.x;
    float a1 = (float)(__bf16)v.y;
    float a2 = (float)(__bf16)v.z;
    float a3 = (float)(__bf16)v.w;
    short4 h = make_short4(f2bs(v.x), f2bs(v.y), f2bs(v.z), f2bs(v.w));
    *(short4*)(Cm + row * DDIM + (lane << 2)) = h;
    float s = a0 * a0 + a1 * a1 + a2 * a2 + a3 * a3;     // self-dot of bf16 row
    #pragma unroll
    for (int off = 32; off; off >>= 1) s += __shfl_xor(s, off, 64);
    if (lane == 0) selfdot[row] = s;
}

// ---------------- symmetric GEMM + fused stats + fused finalize ------------
// 128x128 tile per block over upper-triangle tiles (p>=q); 4 waves each 64x64
// (4x4 frags of 16x16x32 bf16). K staged in 4 chunks of 64; LDS rows padded
// 64->72 shorts (144 B) for conflict-light ds_read_b128.
__device__ __forceinline__ void stage_chunk(short* lds, const short* Cm,
        int tileBase, int kc, int tid) {
    #pragma unroll
    for (int it = 0; it < 4; ++it) {
        int c = (it << 8) + tid;
        int r = c >> 3, c8 = c & 7;
        int4 v = *(const int4*)(Cm + (tileBase + r) * DDIM + (kc << 6) + (c8 << 3));
        *(int4*)&lds[r * 72 + (c8 << 3)] = v;
    }
}

__global__ __launch_bounds__(256) void gemm_sym(const short* __restrict__ Cm,
        const float* __restrict__ selfdot, float* __restrict__ E,
        float* __restrict__ W, float* __restrict__ Lpos, int* __restrict__ cnt,
        const int* __restrict__ index, const float* __restrict__ u,
        float* __restrict__ out) {
    __shared__ short As[128 * 72];
    __shared__ short Bs[128 * 72];
    int tid = threadIdx.x;

    // triangle decode: t -> (p,q), p >= q ; t = p*(p+1)/2 + q
    int t = blockIdx.x;
    int p = (int)((sqrtf(8.0f * (float)t + 1.0f) - 1.0f) * 0.5f);
    while ((p + 1) * (p + 2) / 2 <= t) ++p;
    while (p * (p + 1) / 2 > t) --p;
    int q = t - p * (p + 1) / 2;
    int rowBase = q * 128;          // row band
    int colBase = p * 128;          // col band (>= row band)
    bool offdiag = (p != q);

    int lane = tid & 63;
    int wave = tid >> 6;
    int quad = lane >> 4;
    int l15  = lane & 15;
    int wr = (wave >> 1) * 64;      // wave's row-half within the 128 tile
    int wc = (wave & 1) * 64;       // wave's col-half

    f32x4 acc[4][4];
    #pragma unroll
    for (int a = 0; a < 4; ++a)
        #pragma unroll
        for (int b = 0; b < 4; ++b) acc[a][b] = (f32x4){0.f, 0.f, 0.f, 0.f};

    const short* Bsrc = offdiag ? Bs : As;   // diag tile: B == A
    for (int kc = 0; kc < 4; ++kc) {
        if (kc) __syncthreads();
        stage_chunk(As, Cm, rowBase, kc, tid);
        if (offdiag) stage_chunk(Bs, Cm, colBase, kc, tid);
        __syncthreads();
        #pragma unroll
        for (int kk = 0; kk < 2; ++kk) {
            int ko = (kk << 5) + (quad << 3);
            bf16x8 af[4], bfr[4];
            #pragma unroll
            for (int tt = 0; tt < 4; ++tt)
                af[tt] = *(const bf16x8*)&As[(wr + tt * 16 + l15) * 72 + ko];
            #pragma unroll
            for (int tt = 0; tt < 4; ++tt)
                bfr[tt] = *(const bf16x8*)&Bsrc[(wc + tt * 16 + l15) * 72 + ko];
            #pragma unroll
            for (int rt = 0; rt < 4; ++rt)
                #pragma unroll
                for (int ct = 0; ct < 4; ++ct)
                    acc[rt][ct] = __builtin_amdgcn_mfma_f32_16x16x32_bf16(
                        af[rt], bfr[ct], acc[rt][ct], 0, 0, 0);
        }
    }

    // ---- epilogue: C/D layout col = lane&15, row = quad*4 + reg  [m89/m91]
    float sdr[4][4];                 // self-dot of grow, per (rt, r)
    #pragma unroll
    for (int rt = 0; rt < 4; ++rt)
        #pragma unroll
        for (int r = 0; r < 4; ++r)
            sdr[rt][r] = selfdot[rowBase + wr + rt * 16 + (quad << 2) + r];
    float sdc[4];                    // self-dot of gcol, per ct (lane-varying l15)
    #pragma unroll
    for (int ct = 0; ct < 4; ++ct)
        sdc[ct] = selfdot[colBase + wc + ct * 16 + l15];

    float Ep[4][4] = {}, Wp[4][4] = {};
    float Ec[4] = {}, Wc[4] = {};
    #pragma unroll
    for (int rt = 0; rt < 4; ++rt) {
        #pragma unroll
        for (int ct = 0; ct < 4; ++ct) {
            int gcol = colBase + wc + ct * 16 + l15;
            #pragma unroll
            for (int r = 0; r < 4; ++r) {
                int grow = rowBase + wr + rt * 16 + (quad << 2) + r;
                float d = acc[rt][ct][r];
                float l = (d - sdr[rt][r]) * INVT;       // row-view logit
                float e = __expf(l);
                Ep[rt][r] += e;
                Wp[rt][r] += e * l;
                if (gcol == (grow ^ BSZ)) ag_store(&Lpos[grow], l);
                if (offdiag) {
                    float l2 = (d - sdc[ct]) * INVT;     // col-view (transposed) logit
                    float e2 = __expf(l2);
                    Ec[ct] += e2;
                    Wc[ct] += e2 * l2;
                    if (grow == (gcol ^ BSZ)) ag_store(&Lpos[gcol], l2);
                }
            }
        }
    }
    // row-path reduce over the 16 l15 lanes sharing each row; 1 atomic/row/wave
    #pragma unroll
    for (int rt = 0; rt < 4; ++rt) {
        #pragma unroll
        for (int r = 0; r < 4; ++r) {
            float e = Ep[rt][r], w = Wp[rt][r];
            #pragma unroll
            for (int off = 1; off < 16; off <<= 1) {
                e += __shfl_xor(e, off, 64);
                w += __shfl_xor(w, off, 64);
            }
            if (l15 == 0) {
                int grow = rowBase + wr + rt * 16 + (quad << 2) + r;
                atomicAdd(&E[grow], e);
                atomicAdd(&W[grow], w);
            }
        }
    }
    // col-path reduce over the 4 quads sharing each col; 16 lanes/atomic
    if (offdiag) {
        #pragma unroll
        for (int ct = 0; ct < 4; ++ct) {
            float e = Ec[ct], w = Wc[ct];
            e += __shfl_xor(e, 16, 64);  w += __shfl_xor(w, 16, 64);
            e += __shfl_xor(e, 32, 64);  w += __shfl_xor(w, 32, 64);
            if (quad == 0) {
                int gcol = colBase + wc + ct * 16 + l15;
                atomicAdd(&E[gcol], e);
                atomicAdd(&W[gcol], w);
            }
        }
    }

    // ---- last-block ticket: fused finalize ----
    __shared__ int isLast;
    __threadfence();                 // release our E/W/Lpos writes
    __syncthreads();
    if (tid == 0) isLast = (atomicAdd(cnt, 1) == NTILES - 1);
    __syncthreads();
    if (!isLast) return;
    __threadfence();                 // acquire all blocks' writes

    float* unew = (float*)As;        // reuse LDS: 2048 floats = 8 KB
    for (int b = tid; b < BSZ; b += 256) {
        float lp = ag_load(&Lpos[b]);
        unew[b] = 0.1f * u[index[b]] + 0.9f * (ag_load(&E[b]) - __expf(lp));
    }
    __syncthreads();
    float local = 0.0f;
    for (int i = tid; i < NROW; i += 256) {
        float lp  = ag_load(&Lpos[i]);
        float elp = __expf(lp);
        local += lp - (ag_load(&W[i]) - elp * lp) / unew[i & (BSZ - 1)];
    }
    #pragma unroll
    for (int off = 32; off; off >>= 1) local += __shfl_xor(local, off, 64);
    __shared__ float part[4];
    if (lane == 0) part[wave] = local;
    __syncthreads();
    if (tid == 0) out[0] = -(part[0] + part[1] + part[2] + part[3]) / (float)NROW;
}

extern "C" void kernel_launch(void* const* d_in, const int* in_sizes, int n_in,
                              void* d_out, int out_size, void* d_ws, size_t ws_size,
                              hipStream_t stream) {
    const int*   index = (const int*)d_in[0];
    const float* feats = (const float*)d_in[1];
    const float* u     = (const float*)d_in[2];
    float* out = (float*)d_out;

    // ws: [selfdot|E|W|Lpos] (4x4096 f32 = 64 KB) | cnt | ... | Cm bf16 @128KB
    float* selfdot = (float*)d_ws;
    float* E    = selfdot + NROW;
    float* W    = E + NROW;
    float* Lpos = W + NROW;
    int*   cnt  = (int*)(Lpos + NROW);                   // byte 65536
    short* Cm   = (short*)((char*)d_ws + 131072);        // byte 131072 (no overlap)

    prep_kernel<<<1024, 256, 0, stream>>>(feats, selfdot, E, cnt, Cm);
    gemm_sym<<<NTILES, 256, 0, stream>>>(Cm, selfdot, E, W, Lpos, cnt, index, u, out);
}